// Round 1
// baseline (1718.642 us; speedup 1.0000x reference)
//
#include <hip/hip_runtime.h>
#include <hip/hip_bf16.h>
#include <math.h>

// Problem constants (from reference)
#define BB   2
#define TT   2048
#define DD   768
#define HH   12
#define HD   64
#define MM   (BB*TT)      // 4096 rows for projections

// ---------------------------------------------------------------------------
// Tiled fp32 GEMM: Y = X @ W^T + bias
//   X: (M, K) row-major, W: (N, K) row-major, bias: (N)
//   mode 0: Y[m*N + n]                       (plain row-major)
//   mode 1: Y[((b*H + n/HD)*T + m%T)*HD + n%HD]   ((B,H,T,HD) head layout)
// Tile: 64x64, BK=16, 256 threads, 4x4 microtile per thread.
// ---------------------------------------------------------------------------
__global__ __launch_bounds__(256) void proj_gemm(
    const float* __restrict__ X, const float* __restrict__ W,
    const float* __restrict__ bias, float* __restrict__ Y, int mode)
{
    const int M = MM, N = DD, K = DD;
    __shared__ float As[16][64 + 1];
    __shared__ float Bs[16][64 + 1];

    const int tid = threadIdx.x;
    const int bn = blockIdx.x, bm = blockIdx.y;
    const int tx = tid & 15, ty = tid >> 4;
    const int m0 = bm * 64, n0 = bn * 64;

    float c[4][4] = {};

    for (int k0 = 0; k0 < K; k0 += 16) {
        #pragma unroll
        for (int e = 0; e < 4; e++) {
            int idx = tid + e * 256;        // 0..1023
            int row = idx >> 4, kk = idx & 15;
            As[kk][row] = X[(long)(m0 + row) * K + k0 + kk];
            Bs[kk][row] = W[(long)(n0 + row) * K + k0 + kk];
        }
        __syncthreads();
        #pragma unroll
        for (int kk = 0; kk < 16; kk++) {
            float a[4], b[4];
            #pragma unroll
            for (int i = 0; i < 4; i++) a[i] = As[kk][ty * 4 + i];
            #pragma unroll
            for (int j = 0; j < 4; j++) b[j] = Bs[kk][tx * 4 + j];
            #pragma unroll
            for (int i = 0; i < 4; i++)
                #pragma unroll
                for (int j = 0; j < 4; j++)
                    c[i][j] += a[i] * b[j];
        }
        __syncthreads();
    }

    #pragma unroll
    for (int i = 0; i < 4; i++) {
        int m = m0 + ty * 4 + i;
        #pragma unroll
        for (int j = 0; j < 4; j++) {
            int n = n0 + tx * 4 + j;
            float val = c[i][j] + bias[n];
            if (mode == 0) {
                Y[(long)m * N + n] = val;
            } else {
                int b_ = m >> 11;          // m / T
                int t_ = m & (TT - 1);     // m % T
                int h_ = n >> 6;           // n / HD
                int d_ = n & (HD - 1);     // n % HD
                Y[(((long)b_ * HH + h_) * TT + t_) * HD + d_] = val;
            }
        }
    }
}

// ---------------------------------------------------------------------------
// BigBird flash attention, fp32.
// Block = 256 threads handles one (b, h, 32-q-row tile).
// Streams 64-key tiles; skips tiles whose 32x64 mask block is all-false.
// Thread (tid): q row r = tid>>3, key-slice g = tid&7 (8 keys), d-slice = g*8.
// ---------------------------------------------------------------------------
__device__ __forceinline__ int mget(const unsigned char* m8, const int* m32,
                                    bool u8, long i)
{
    return u8 ? (int)m8[i] : m32[i];
}

__global__ __launch_bounds__(256) void bigbird_attn(
    const float* __restrict__ Q, const float* __restrict__ Kg,
    const float* __restrict__ V, const void* __restrict__ maskp,
    float* __restrict__ O)
{
    constexpr int QT = 32, KT = 64;
    const float scale = 0.125f;   // 64^-0.5

    const int qt = blockIdx.x, h = blockIdx.y, b = blockIdx.z;
    const int tid = threadIdx.x;

    const unsigned char* m8 = (const unsigned char*)maskp;
    const int* m32 = (const int*)maskp;
    // mask[0][1] is true (global row 0). uint8 -> byte1==1 ; int32 LE -> byte1==0
    const bool u8 = (m8[1] != 0);

    __shared__ float qs[QT][HD + 1];
    __shared__ float ks[KT][HD + 1];
    __shared__ float vs[KT][HD + 1];
    __shared__ float ps[QT][KT + 1];

    const int q0 = qt * QT;
    const float* qb = Q + (((long)b * HH + h) * TT + q0) * HD;
    for (int i = tid; i < QT * HD; i += 256)
        qs[i >> 6][i & 63] = qb[i];
    // visibility of qs ensured by the __syncthreads_or below

    const int r = tid >> 3;       // q row within tile
    const int g = tid & 7;        // key/d slice group
    const int dsl = g * 8;

    float acc[8] = {0.f, 0.f, 0.f, 0.f, 0.f, 0.f, 0.f, 0.f};
    float mrow = -INFINITY, lrow = 0.f;

    const float* kb = Kg + (((long)b * HH + h) * TT) * HD;
    const float* vb = V + (((long)b * HH + h) * TT) * HD;

    for (int k0 = 0; k0 < TT; k0 += KT) {
        // ---- block-level skip check over the 32x64 mask tile ----
        int any = 0;
        #pragma unroll
        for (int e = 0; e < 8; e++) {
            int idx = tid + e * 256;
            int qq = idx >> 6, kk = idx & 63;
            any |= mget(m8, m32, u8, (long)(q0 + qq) * TT + k0 + kk);
        }
        if (!__syncthreads_or(any)) continue;   // barrier: protects ks/vs reuse

        // ---- stage K, V tiles ----
        for (int i = tid; i < KT * HD; i += 256) {
            int row = i >> 6, d = i & 63;
            ks[row][d] = kb[(long)k0 * HD + i];
            vs[row][d] = vb[(long)k0 * HD + i];
        }
        __syncthreads();

        // ---- scores: s[j] = q[r] . k[g*8+j] ----
        float s[8] = {0.f, 0.f, 0.f, 0.f, 0.f, 0.f, 0.f, 0.f};
        #pragma unroll 4
        for (int d = 0; d < HD; d++) {
            float qv = qs[r][d];
            #pragma unroll
            for (int j = 0; j < 8; j++)
                s[j] += qv * ks[g * 8 + j][d];
        }

        // ---- mask + scale + row max ----
        float tm = -INFINITY;
        #pragma unroll
        for (int j = 0; j < 8; j++) {
            long mi = (long)(q0 + r) * TT + k0 + g * 8 + j;
            int mv = mget(m8, m32, u8, mi);
            s[j] = mv ? s[j] * scale : -INFINITY;
            tm = fmaxf(tm, s[j]);
        }
        #pragma unroll
        for (int off = 1; off < 8; off <<= 1)
            tm = fmaxf(tm, __shfl_xor(tm, off, 64));

        float newm = fmaxf(mrow, tm);
        // corr: if both -inf (nothing seen yet & tile row fully masked) -> 1
        float corr = (mrow == newm) ? 1.f : __expf(mrow - newm);

        float psum = 0.f;
        #pragma unroll
        for (int j = 0; j < 8; j++) {
            float p = (s[j] == -INFINITY) ? 0.f : __expf(s[j] - newm);
            ps[r][g * 8 + j] = p;
            psum += p;
        }
        #pragma unroll
        for (int off = 1; off < 8; off <<= 1)
            psum += __shfl_xor(psum, off, 64);

        lrow = lrow * corr + psum;
        mrow = newm;
        #pragma unroll
        for (int j = 0; j < 8; j++) acc[j] *= corr;

        // ---- PV: acc[j] += sum_k p[r][k] * v[k][dsl+j] ----
        // ps written/read within the same wave (8-lane row groups) -> in-order LDS
        #pragma unroll 4
        for (int kk = 0; kk < KT; kk++) {
            float p = ps[r][kk];
            #pragma unroll
            for (int j = 0; j < 8; j++)
                acc[j] += p * vs[kk][dsl + j];
        }
        // next-iteration __syncthreads_or separates PV reads from restaging
    }

    // every row has the 32 global columns unmasked -> lrow > 0 always
    const float inv = 1.f / lrow;
    long ob = ((long)b * TT + q0 + r) * DD + h * HD + dsl;
    #pragma unroll
    for (int j = 0; j < 8; j++)
        O[ob + j] = acc[j] * inv;
}

// ---------------------------------------------------------------------------
extern "C" void kernel_launch(void* const* d_in, const int* in_sizes, int n_in,
                              void* d_out, int out_size, void* d_ws, size_t ws_size,
                              hipStream_t stream)
{
    const float* x  = (const float*)d_in[0];
    const float* Wq = (const float*)d_in[1];
    const float* bq = (const float*)d_in[2];
    const float* Wk = (const float*)d_in[3];
    const float* bk = (const float*)d_in[4];
    const float* Wv = (const float*)d_in[5];
    const float* bv = (const float*)d_in[6];
    const float* Wo = (const float*)d_in[7];
    const float* bo = (const float*)d_in[8];
    const void*  mask = d_in[9];

    const long BTD = (long)BB * TT * DD;   // 3,145,728 floats
    float* ws = (float*)d_ws;
    float* q  = ws;
    float* k  = ws + BTD;
    float* v  = ws + 2 * BTD;
    float* ao = ws + 3 * BTD;

    dim3 gemm_grid(DD / 64, MM / 64);      // (12, 64)
    proj_gemm<<<gemm_grid, 256, 0, stream>>>(x, Wq, bq, q, 1);
    proj_gemm<<<gemm_grid, 256, 0, stream>>>(x, Wk, bk, k, 1);
    proj_gemm<<<gemm_grid, 256, 0, stream>>>(x, Wv, bv, v, 1);

    dim3 attn_grid(TT / 32, HH, BB);       // (64, 12, 2)
    bigbird_attn<<<attn_grid, 256, 0, stream>>>(q, k, v, mask, ao);

    proj_gemm<<<gemm_grid, 256, 0, stream>>>(ao, Wo, bo, (float*)d_out, 0);
}

// Round 2
// 635.215 us; speedup vs baseline: 2.7056x; 2.7056x over previous
//
#include <hip/hip_runtime.h>
#include <hip/hip_bf16.h>
#include <math.h>

#define BB   2
#define TT   2048
#define DD   768
#define HH   12
#define HD   64
#define MM   (BB*TT)

// ---------------------------------------------------------------------------
// Tiled fp32 GEMM: Y = X @ W^T + bias   (unchanged from round 1)
// ---------------------------------------------------------------------------
__global__ __launch_bounds__(256) void proj_gemm(
    const float* __restrict__ X, const float* __restrict__ W,
    const float* __restrict__ bias, float* __restrict__ Y, int mode)
{
    const int N = DD, K = DD;
    __shared__ float As[16][64 + 1];
    __shared__ float Bs[16][64 + 1];

    const int tid = threadIdx.x;
    const int bn = blockIdx.x, bm = blockIdx.y;
    const int tx = tid & 15, ty = tid >> 4;
    const int m0 = bm * 64, n0 = bn * 64;

    float c[4][4] = {};

    for (int k0 = 0; k0 < K; k0 += 16) {
        #pragma unroll
        for (int e = 0; e < 4; e++) {
            int idx = tid + e * 256;
            int row = idx >> 4, kk = idx & 15;
            As[kk][row] = X[(long)(m0 + row) * K + k0 + kk];
            Bs[kk][row] = W[(long)(n0 + row) * K + k0 + kk];
        }
        __syncthreads();
        #pragma unroll
        for (int kk = 0; kk < 16; kk++) {
            float a[4], b[4];
            #pragma unroll
            for (int i = 0; i < 4; i++) a[i] = As[kk][ty * 4 + i];
            #pragma unroll
            for (int j = 0; j < 4; j++) b[j] = Bs[kk][tx * 4 + j];
            #pragma unroll
            for (int i = 0; i < 4; i++)
                #pragma unroll
                for (int j = 0; j < 4; j++)
                    c[i][j] += a[i] * b[j];
        }
        __syncthreads();
    }

    #pragma unroll
    for (int i = 0; i < 4; i++) {
        int m = m0 + ty * 4 + i;
        #pragma unroll
        for (int j = 0; j < 4; j++) {
            int n = n0 + tx * 4 + j;
            float val = c[i][j] + bias[n];
            if (mode == 0) {
                Y[(long)m * N + n] = val;
            } else {
                int b_ = m >> 11;
                int t_ = m & (TT - 1);
                int h_ = n >> 6;
                int d_ = n & (HD - 1);
                Y[(((long)b_ * HH + h_) * TT + t_) * HD + d_] = val;
            }
        }
    }
}

// ---------------------------------------------------------------------------
// Extract the 16 random key columns per row (rows 32..2047).
// Randoms are exactly: mask[r][c] && c>=32 && |c-r|>64  (by construction).
// One 64-lane block per row; shfl prefix-scan compaction. Pads with -1.
// ---------------------------------------------------------------------------
__global__ __launch_bounds__(64) void extract_rand(
    const void* __restrict__ maskp, int* __restrict__ rand_idx)
{
    const int row = blockIdx.x + 32;
    const int lane = threadIdx.x;
    const unsigned char* m8 = (const unsigned char*)maskp;
    const int* m32 = (const int*)maskp;
    const bool u8 = (m8[1] != 0);   // mask[0][1] is true: u8 -> byte1==1

    int loc[16];
    int cnt = 0;
    const int c0 = lane * 32;
    for (int t = 0; t < 32; t++) {
        int c = c0 + t;
        int d = c - row;
        if (c >= 32 && (d > 64 || d < -64)) {
            int mv = u8 ? (int)m8[(long)row * TT + c] : m32[(long)row * TT + c];
            if (mv && cnt < 16) loc[cnt++] = c;
        }
    }
    int incl = cnt;
    for (int d = 1; d < 64; d <<= 1) {
        int n = __shfl_up(incl, d, 64);
        if (lane >= d) incl += n;
    }
    const int excl = incl - cnt;
    for (int i = 0; i < cnt; i++) {
        int p = excl + i;
        if (p < 16) rand_idx[(long)row * 16 + p] = loc[i];
    }
    const int total = __shfl(incl, 63, 64);
    if (lane == 0)
        for (int p = total; p < 16; p++) rand_idx[(long)row * 16 + p] = -1;
}

// ---------------------------------------------------------------------------
// Dense global rows 0..31: each block does a 256-col chunk, flash partial.
// part layout: [(b*H+h)][chunk(8)][row(32)][66] = {m, l, acc[64]} unnormalized
// ---------------------------------------------------------------------------
__global__ __launch_bounds__(256) void bb_dense_rows(
    const float* __restrict__ Q, const float* __restrict__ Kg,
    const float* __restrict__ V, float* __restrict__ part)
{
    const int ch = blockIdx.x, h = blockIdx.y, b = blockIdx.z;
    const int tid = threadIdx.x;
    __shared__ float qs[32][65];
    __shared__ float ks[64][65];
    __shared__ float vs[64][65];
    __shared__ float ps[32][65];

    const float* qb = Q + ((long)b * HH + h) * TT * HD;   // rows 0..31
    for (int i = tid; i < 32 * 64; i += 256) qs[i >> 6][i & 63] = qb[i];

    const int r = tid >> 3, g = tid & 7, dsl = g * 8;
    float acc[8] = {};
    float mrow = -INFINITY, lrow = 0.f;
    const float* kb = Kg + ((long)b * HH + h) * TT * HD;
    const float* vb = V + ((long)b * HH + h) * TT * HD;

    for (int t = 0; t < 4; t++) {
        const int k0 = ch * 256 + t * 64;
        __syncthreads();
        for (int i = tid; i < 64 * 64; i += 256) {
            ks[i >> 6][i & 63] = kb[(long)k0 * 64 + i];
            vs[i >> 6][i & 63] = vb[(long)k0 * 64 + i];
        }
        __syncthreads();
        float s[8] = {};
        for (int d = 0; d < 64; d++) {
            float qv = qs[r][d];
            #pragma unroll
            for (int j = 0; j < 8; j++) s[j] += qv * ks[g * 8 + j][d];
        }
        float tm = -INFINITY;
        #pragma unroll
        for (int j = 0; j < 8; j++) { s[j] *= 0.125f; tm = fmaxf(tm, s[j]); }
        #pragma unroll
        for (int o = 1; o < 8; o <<= 1) tm = fmaxf(tm, __shfl_xor(tm, o, 64));
        const float newm = fmaxf(mrow, tm);
        const float corr = (mrow == newm) ? 1.f : __expf(mrow - newm);
        float psum = 0.f;
        #pragma unroll
        for (int j = 0; j < 8; j++) {
            float p = __expf(s[j] - newm);
            ps[r][g * 8 + j] = p; psum += p;
        }
        #pragma unroll
        for (int o = 1; o < 8; o <<= 1) psum += __shfl_xor(psum, o, 64);
        lrow = lrow * corr + psum; mrow = newm;
        #pragma unroll
        for (int j = 0; j < 8; j++) acc[j] *= corr;
        #pragma unroll 4
        for (int kk = 0; kk < 64; kk++) {
            float p = ps[r][kk];
            #pragma unroll
            for (int j = 0; j < 8; j++) acc[j] += p * vs[kk][dsl + j];
        }
    }
    float* pb = part + ((((long)b * HH + h) * 8 + ch) * 32 + r) * 66;
    if (g == 0) { pb[0] = mrow; pb[1] = lrow; }
    #pragma unroll
    for (int j = 0; j < 8; j++) pb[2 + dsl + j] = acc[j];
}

__global__ __launch_bounds__(256) void bb_dense_combine(
    const float* __restrict__ part, float* __restrict__ Ao)
{
    const int h = blockIdx.x, b = blockIdx.y;
    const int tid = threadIdx.x;
    const int r = tid >> 3, dsl = (tid & 7) * 8;
    const float* pb = part + (((long)b * HH + h) * 8 * 32 + r) * 66;
    float M = -INFINITY;
    #pragma unroll
    for (int c = 0; c < 8; c++) M = fmaxf(M, pb[(long)c * 32 * 66]);
    float L = 0.f, o[8] = {};
    #pragma unroll
    for (int c = 0; c < 8; c++) {
        const float* pc = pb + (long)c * 32 * 66;
        const float w = __expf(pc[0] - M);
        L += w * pc[1];
        #pragma unroll
        for (int j = 0; j < 8; j++) o[j] += w * pc[2 + dsl + j];
    }
    const float inv = 1.f / L;
    const long ob = ((long)b * TT + r) * DD + h * HD + dsl;
    #pragma unroll
    for (int j = 0; j < 8; j++) Ao[ob + j] = o[j] * inv;
}

// ---------------------------------------------------------------------------
// Sparse rows 32..2047. Per 32-row q-tile: G (cols 0..31, all active) +
// band chunks [max(32,q0-64) .. q0+95] with |c-row|<=64 predicate +
// 16 gathered random cols per row. Exact partition of the mask's active set.
// ---------------------------------------------------------------------------
__global__ __launch_bounds__(256) void bb_sparse(
    const float* __restrict__ Q, const float* __restrict__ Kg,
    const float* __restrict__ V, const int* __restrict__ rand_idx,
    float* __restrict__ Ao)
{
    const int q0 = (blockIdx.x + 1) * 32;
    const int h = blockIdx.y, b = blockIdx.z;
    const int tid = threadIdx.x;
    __shared__ float qs[32][65];
    __shared__ float ks[64][65];
    __shared__ float vs[64][65];
    __shared__ float ps[32][65];

    const float* qb = Q + (((long)b * HH + h) * TT + q0) * HD;
    for (int i = tid; i < 32 * 64; i += 256) qs[i >> 6][i & 63] = qb[i];

    const int r = tid >> 3, g = tid & 7, dsl = g * 8;
    const int row = q0 + r;
    float acc[8] = {};
    float mrow = -INFINITY, lrow = 0.f;
    const float* kb = Kg + ((long)b * HH + h) * TT * HD;
    const float* vb = V + ((long)b * HH + h) * TT * HD;

    // ---- G: cols 0..31 (always active), 4 keys/thread ----
    for (int i = tid; i < 32 * 64; i += 256) {
        ks[i >> 6][i & 63] = kb[i];
        vs[i >> 6][i & 63] = vb[i];
    }
    __syncthreads();
    {
        float s[4] = {};
        for (int d = 0; d < 64; d++) {
            float qv = qs[r][d];
            #pragma unroll
            for (int j = 0; j < 4; j++) s[j] += qv * ks[g * 4 + j][d];
        }
        float tm = -INFINITY;
        #pragma unroll
        for (int j = 0; j < 4; j++) { s[j] *= 0.125f; tm = fmaxf(tm, s[j]); }
        #pragma unroll
        for (int o = 1; o < 8; o <<= 1) tm = fmaxf(tm, __shfl_xor(tm, o, 64));
        const float newm = tm;           // mrow was -inf
        float psum = 0.f;
        #pragma unroll
        for (int j = 0; j < 4; j++) {
            float p = __expf(s[j] - newm);
            ps[r][g * 4 + j] = p; psum += p;
        }
        #pragma unroll
        for (int o = 1; o < 8; o <<= 1) psum += __shfl_xor(psum, o, 64);
        lrow = psum; mrow = newm;
        #pragma unroll 4
        for (int kk = 0; kk < 32; kk++) {
            float p = ps[r][kk];
            #pragma unroll
            for (int j = 0; j < 8; j++) acc[j] += p * vs[kk][dsl + j];
        }
    }

    // ---- L: band chunks, predicate |c-row|<=64 ----
    const int lo = max(32, q0 - 64);
    const int hi = min(TT - 1, q0 + 95);
    for (int c0 = lo; c0 <= hi; c0 += 64) {
        const int W = min(64, hi - c0 + 1);
        __syncthreads();
        for (int i = tid; i < W * 64; i += 256) {
            ks[i >> 6][i & 63] = kb[(long)c0 * 64 + i];
            vs[i >> 6][i & 63] = vb[(long)c0 * 64 + i];
        }
        __syncthreads();
        float s[8] = {};
        for (int d = 0; d < 64; d++) {
            float qv = qs[r][d];
            #pragma unroll
            for (int j = 0; j < 8; j++) s[j] += qv * ks[g * 8 + j][d];
        }
        float tm = -INFINITY;
        #pragma unroll
        for (int j = 0; j < 8; j++) {
            const int kk = g * 8 + j;
            const int dlt = c0 + kk - row;
            const bool act = (kk < W) && dlt <= 64 && dlt >= -64;
            s[j] = act ? s[j] * 0.125f : -INFINITY;
            tm = fmaxf(tm, s[j]);
        }
        #pragma unroll
        for (int o = 1; o < 8; o <<= 1) tm = fmaxf(tm, __shfl_xor(tm, o, 64));
        const float newm = fmaxf(mrow, tm);
        const float corr = (mrow == newm) ? 1.f : __expf(mrow - newm);
        float psum = 0.f;
        #pragma unroll
        for (int j = 0; j < 8; j++) {
            float p = (s[j] == -INFINITY) ? 0.f : __expf(s[j] - newm);
            ps[r][g * 8 + j] = p; psum += p;
        }
        #pragma unroll
        for (int o = 1; o < 8; o <<= 1) psum += __shfl_xor(psum, o, 64);
        lrow = lrow * corr + psum; mrow = newm;
        #pragma unroll
        for (int j = 0; j < 8; j++) acc[j] *= corr;
        #pragma unroll 4
        for (int kk = 0; kk < W; kk++) {
            float p = ps[r][kk];
            #pragma unroll
            for (int j = 0; j < 8; j++) acc[j] += p * vs[kk][dsl + j];
        }
    }

    // ---- R: 16 random cols/row, 2 per thread, gathered from global ----
    const int* rr = rand_idx + (long)row * 16;
    {
        float s2[2];
        #pragma unroll
        for (int t = 0; t < 2; t++) {
            const int c = rr[g * 2 + t];
            const float4* kp = (const float4*)(kb + (long)max(c, 0) * HD);
            float sv = 0.f;
            #pragma unroll
            for (int d4 = 0; d4 < 16; d4++) {
                const float4 kv = kp[d4];
                sv += qs[r][d4 * 4 + 0] * kv.x + qs[r][d4 * 4 + 1] * kv.y
                    + qs[r][d4 * 4 + 2] * kv.z + qs[r][d4 * 4 + 3] * kv.w;
            }
            s2[t] = (c >= 0) ? sv * 0.125f : -INFINITY;
        }
        float tm = fmaxf(s2[0], s2[1]);
        #pragma unroll
        for (int o = 1; o < 8; o <<= 1) tm = fmaxf(tm, __shfl_xor(tm, o, 64));
        const float newm = fmaxf(mrow, tm);
        const float corr = (mrow == newm) ? 1.f : __expf(mrow - newm);
        float psum = 0.f;
        #pragma unroll
        for (int t = 0; t < 2; t++) {
            float p = (s2[t] == -INFINITY) ? 0.f : __expf(s2[t] - newm);
            ps[r][g * 2 + t] = p; psum += p;
        }
        #pragma unroll
        for (int o = 1; o < 8; o <<= 1) psum += __shfl_xor(psum, o, 64);
        lrow = lrow * corr + psum; mrow = newm;
        #pragma unroll
        for (int j = 0; j < 8; j++) acc[j] *= corr;
        #pragma unroll 4
        for (int kk = 0; kk < 16; kk++) {
            const float p = ps[r][kk];
            const int c = max(rr[kk], 0);
            const float4* vp = (const float4*)(vb + (long)c * HD + dsl);
            const float4 v0 = vp[0], v1 = vp[1];
            acc[0] += p * v0.x; acc[1] += p * v0.y;
            acc[2] += p * v0.z; acc[3] += p * v0.w;
            acc[4] += p * v1.x; acc[5] += p * v1.y;
            acc[6] += p * v1.z; acc[7] += p * v1.w;
        }
    }

    const float inv = 1.f / lrow;
    const long ob = ((long)b * TT + row) * DD + h * HD + dsl;
    #pragma unroll
    for (int j = 0; j < 8; j++) Ao[ob + j] = acc[j] * inv;
}

// ---------------------------------------------------------------------------
extern "C" void kernel_launch(void* const* d_in, const int* in_sizes, int n_in,
                              void* d_out, int out_size, void* d_ws, size_t ws_size,
                              hipStream_t stream)
{
    const float* x  = (const float*)d_in[0];
    const float* Wq = (const float*)d_in[1];
    const float* bq = (const float*)d_in[2];
    const float* Wk = (const float*)d_in[3];
    const float* bk = (const float*)d_in[4];
    const float* Wv = (const float*)d_in[5];
    const float* bv = (const float*)d_in[6];
    const float* Wo = (const float*)d_in[7];
    const float* bo = (const float*)d_in[8];
    const void*  mask = d_in[9];

    const long BTD = (long)BB * TT * DD;
    float* ws = (float*)d_ws;
    float* q  = ws;
    float* k  = ws + BTD;
    float* v  = ws + 2 * BTD;
    float* ao = ws + 3 * BTD;
    int*   rand_idx = (int*)(ws + 4 * BTD);                 // 2048*16 ints
    float* part = (float*)(rand_idx + (long)TT * 16);       // 2*12*8*32*66 floats

    extract_rand<<<TT - 32, 64, 0, stream>>>(mask, rand_idx);

    dim3 gemm_grid(DD / 64, MM / 64);
    proj_gemm<<<gemm_grid, 256, 0, stream>>>(x, Wq, bq, q, 1);
    proj_gemm<<<gemm_grid, 256, 0, stream>>>(x, Wk, bk, k, 1);
    proj_gemm<<<gemm_grid, 256, 0, stream>>>(x, Wv, bv, v, 1);

    bb_dense_rows<<<dim3(8, HH, BB), 256, 0, stream>>>(q, k, v, part);
    bb_dense_combine<<<dim3(HH, BB), 256, 0, stream>>>(part, ao);
    bb_sparse<<<dim3(TT / 32 - 1, HH, BB), 256, 0, stream>>>(q, k, v, rand_idx, ao);

    proj_gemm<<<gemm_grid, 256, 0, stream>>>(ao, Wo, bo, (float*)d_out, 0);
}

// Round 3
// 277.636 us; speedup vs baseline: 6.1903x; 2.2879x over previous
//
#include <hip/hip_runtime.h>
#include <hip/hip_bf16.h>
#include <math.h>

#define BB   2
#define TT   2048
#define DD   768
#define HH   12
#define HD   64
#define MM   (BB*TT)
#define BTD  ((long)BB*TT*DD)

typedef __bf16 bf16x8 __attribute__((ext_vector_type(8)));
typedef __bf16 bf16x4 __attribute__((ext_vector_type(4)));
typedef float  f32x4  __attribute__((ext_vector_type(4)));

// ---------------------------------------------------------------------------
// fp32 -> bf16 convert (vectorized float4 -> bf16x4)
// ---------------------------------------------------------------------------
__global__ __launch_bounds__(256) void cvt_bf16(
    const float* __restrict__ in, __bf16* __restrict__ out, int n4)
{
    const int i = blockIdx.x * 256 + threadIdx.x;
    if (i < n4) {
        const float4 v = ((const float4*)in)[i];
        bf16x4 o;
        o.x = (__bf16)v.x; o.y = (__bf16)v.y;
        o.z = (__bf16)v.z; o.w = (__bf16)v.w;
        ((bf16x4*)out)[i] = o;
    }
}

// ---------------------------------------------------------------------------
// bf16 MFMA GEMM: Y = A @ B^T + bias
//   A: (4096, 768) bf16 row-major; Bw: (N, 768) bf16 row-major.
//   mode 0: Y fp32 row-major (N=768), bias b0
//   mode 1: N=2304 (q|k|v): Y base of 3 contiguous (B,H,T,HD) fp32 buffers,
//           bias b0/b1/b2 per 768-chunk.
// 128x128 tile, BK=32, 256 threads (4 waves, 2x2), global_load_lds width 16.
// ---------------------------------------------------------------------------
__global__ __launch_bounds__(256) void mfma_gemm(
    const __bf16* __restrict__ A, const __bf16* __restrict__ Bw,
    const float* __restrict__ b0, const float* __restrict__ b1,
    const float* __restrict__ b2, float* __restrict__ Y,
    int N, int mode)
{
    constexpr int K = DD;
    __shared__ __bf16 As[128 * 32];
    __shared__ __bf16 Bs[128 * 32];

    const int tid  = threadIdx.x;
    const int wid  = tid >> 6, lane = tid & 63;
    const int m0   = blockIdx.y * 128, n0 = blockIdx.x * 128;
    const int wr   = wid >> 1, wc = wid & 1;

    f32x4 acc[4][4] = {};

    const char* Ag = (const char*)(A + (long)m0 * K);
    const char* Bg = (const char*)(Bw + (long)n0 * K);

    for (int k0 = 0; k0 < K; k0 += 32) {
        #pragma unroll
        for (int c = 0; c < 2; c++) {
            const int o   = wid * 2048 + c * 1024 + lane * 16;
            const int row = o >> 6, kb = o & 63;
            const long goff = (long)row * (K * 2) + k0 * 2 + kb;
            __builtin_amdgcn_global_load_lds(
                (const __attribute__((address_space(1))) void*)(Ag + goff),
                (__attribute__((address_space(3))) void*)((char*)As + wid * 2048 + c * 1024),
                16, 0, 0);
            __builtin_amdgcn_global_load_lds(
                (const __attribute__((address_space(1))) void*)(Bg + goff),
                (__attribute__((address_space(3))) void*)((char*)Bs + wid * 2048 + c * 1024),
                16, 0, 0);
        }
        __syncthreads();

        bf16x8 af[4], bfr[4];
        #pragma unroll
        for (int m = 0; m < 4; m++)
            af[m] = *(const bf16x8*)(As + ((wr * 64 + m * 16 + (lane & 15)) * 32 + (lane >> 4) * 8));
        #pragma unroll
        for (int n = 0; n < 4; n++)
            bfr[n] = *(const bf16x8*)(Bs + ((wc * 64 + n * 16 + (lane & 15)) * 32 + (lane >> 4) * 8));
        #pragma unroll
        for (int m = 0; m < 4; m++)
            #pragma unroll
            for (int n = 0; n < 4; n++)
                acc[m][n] = __builtin_amdgcn_mfma_f32_16x16x32_bf16(
                    af[m], bfr[n], acc[m][n], 0, 0, 0);
        __syncthreads();
    }

    const int fq = lane >> 4, fr = lane & 15;
    #pragma unroll
    for (int m = 0; m < 4; m++) {
        const int grow = m0 + wr * 64 + m * 16 + fq * 4;
        #pragma unroll
        for (int n = 0; n < 4; n++) {
            const int col = n0 + wc * 64 + n * 16 + fr;
            if (mode == 0) {
                const float bias = b0[col];
                #pragma unroll
                for (int j = 0; j < 4; j++)
                    Y[(long)(grow + j) * N + col] = acc[m][n][j] + bias;
            } else {
                const int which = col / DD;
                const int nn = col - which * DD;
                const float* bp = which == 0 ? b0 : (which == 1 ? b1 : b2);
                const float bias = bp[nn];
                const int h_ = nn >> 6, d_ = nn & 63;
                float* base = Y + (long)which * BTD;
                #pragma unroll
                for (int j = 0; j < 4; j++) {
                    const int row = grow + j;
                    const int b_ = row >> 11, t_ = row & (TT - 1);
                    base[(((long)b_ * HH + h_) * TT + t_) * HD + d_] = acc[m][n][j] + bias;
                }
            }
        }
    }
}

// ---------------------------------------------------------------------------
// Extract the 16 random key columns per row (rows 32..2047).
// ---------------------------------------------------------------------------
__global__ __launch_bounds__(64) void extract_rand(
    const void* __restrict__ maskp, int* __restrict__ rand_idx)
{
    const int row = blockIdx.x + 32;
    const int lane = threadIdx.x;
    const unsigned char* m8 = (const unsigned char*)maskp;
    const int* m32 = (const int*)maskp;
    const bool u8 = (m8[1] != 0);

    int loc[16];
    int cnt = 0;
    const int c0 = lane * 32;
    for (int t = 0; t < 32; t++) {
        int c = c0 + t;
        int d = c - row;
        if (c >= 32 && (d > 64 || d < -64)) {
            int mv = u8 ? (int)m8[(long)row * TT + c] : m32[(long)row * TT + c];
            if (mv && cnt < 16) loc[cnt++] = c;
        }
    }
    int incl = cnt;
    for (int d = 1; d < 64; d <<= 1) {
        int n = __shfl_up(incl, d, 64);
        if (lane >= d) incl += n;
    }
    const int excl = incl - cnt;
    for (int i = 0; i < cnt; i++) {
        int p = excl + i;
        if (p < 16) rand_idx[(long)row * 16 + p] = loc[i];
    }
    const int total = __shfl(incl, 63, 64);
    if (lane == 0)
        for (int p = total; p < 16; p++) rand_idx[(long)row * 16 + p] = -1;
}

// ---------------------------------------------------------------------------
// Dense global rows 0..31: flash partials over 256-col chunks.
// ---------------------------------------------------------------------------
__global__ __launch_bounds__(256) void bb_dense_rows(
    const float* __restrict__ Q, const float* __restrict__ Kg,
    const float* __restrict__ V, float* __restrict__ part)
{
    const int ch = blockIdx.x, h = blockIdx.y, b = blockIdx.z;
    const int tid = threadIdx.x;
    __shared__ float qs[32][65];
    __shared__ float ks[64][65];
    __shared__ float vs[64][65];
    __shared__ float ps[32][65];

    const float* qb = Q + ((long)b * HH + h) * TT * HD;
    for (int i = tid; i < 32 * 64; i += 256) qs[i >> 6][i & 63] = qb[i];

    const int r = tid >> 3, g = tid & 7, dsl = g * 8;
    float acc[8] = {};
    float mrow = -INFINITY, lrow = 0.f;
    const float* kb = Kg + ((long)b * HH + h) * TT * HD;
    const float* vb = V + ((long)b * HH + h) * TT * HD;

    for (int t = 0; t < 4; t++) {
        const int k0 = ch * 256 + t * 64;
        __syncthreads();
        for (int i = tid; i < 64 * 64; i += 256) {
            ks[i >> 6][i & 63] = kb[(long)k0 * 64 + i];
            vs[i >> 6][i & 63] = vb[(long)k0 * 64 + i];
        }
        __syncthreads();
        float s[8] = {};
        for (int d = 0; d < 64; d++) {
            float qv = qs[r][d];
            #pragma unroll
            for (int j = 0; j < 8; j++) s[j] += qv * ks[g * 8 + j][d];
        }
        float tm = -INFINITY;
        #pragma unroll
        for (int j = 0; j < 8; j++) { s[j] *= 0.125f; tm = fmaxf(tm, s[j]); }
        #pragma unroll
        for (int o = 1; o < 8; o <<= 1) tm = fmaxf(tm, __shfl_xor(tm, o, 64));
        const float newm = fmaxf(mrow, tm);
        const float corr = (mrow == newm) ? 1.f : __expf(mrow - newm);
        float psum = 0.f;
        #pragma unroll
        for (int j = 0; j < 8; j++) {
            float p = __expf(s[j] - newm);
            ps[r][g * 8 + j] = p; psum += p;
        }
        #pragma unroll
        for (int o = 1; o < 8; o <<= 1) psum += __shfl_xor(psum, o, 64);
        lrow = lrow * corr + psum; mrow = newm;
        #pragma unroll
        for (int j = 0; j < 8; j++) acc[j] *= corr;
        #pragma unroll 4
        for (int kk = 0; kk < 64; kk++) {
            float p = ps[r][kk];
            #pragma unroll
            for (int j = 0; j < 8; j++) acc[j] += p * vs[kk][dsl + j];
        }
    }
    float* pb = part + ((((long)b * HH + h) * 8 + ch) * 32 + r) * 66;
    if (g == 0) { pb[0] = mrow; pb[1] = lrow; }
    #pragma unroll
    for (int j = 0; j < 8; j++) pb[2 + dsl + j] = acc[j];
}

__global__ __launch_bounds__(256) void bb_dense_combine(
    const float* __restrict__ part, __bf16* __restrict__ Ao)
{
    const int h = blockIdx.x, b = blockIdx.y;
    const int tid = threadIdx.x;
    const int r = tid >> 3, dsl = (tid & 7) * 8;
    const float* pb = part + (((long)b * HH + h) * 8 * 32 + r) * 66;
    float M = -INFINITY;
    #pragma unroll
    for (int c = 0; c < 8; c++) M = fmaxf(M, pb[(long)c * 32 * 66]);
    float L = 0.f, o[8] = {};
    #pragma unroll
    for (int c = 0; c < 8; c++) {
        const float* pc = pb + (long)c * 32 * 66;
        const float w = __expf(pc[0] - M);
        L += w * pc[1];
        #pragma unroll
        for (int j = 0; j < 8; j++) o[j] += w * pc[2 + dsl + j];
    }
    const float inv = 1.f / L;
    const long ob = ((long)b * TT + r) * DD + h * HD + dsl;
    #pragma unroll
    for (int j = 0; j < 8; j++) Ao[ob + j] = (__bf16)(o[j] * inv);
}

// ---------------------------------------------------------------------------
// Sparse rows 32..2047: G + band + 16 randoms (exact mask partition).
// ---------------------------------------------------------------------------
__global__ __launch_bounds__(256) void bb_sparse(
    const float* __restrict__ Q, const float* __restrict__ Kg,
    const float* __restrict__ V, const int* __restrict__ rand_idx,
    __bf16* __restrict__ Ao)
{
    const int q0 = (blockIdx.x + 1) * 32;
    const int h = blockIdx.y, b = blockIdx.z;
    const int tid = threadIdx.x;
    __shared__ float qs[32][65];
    __shared__ float ks[64][65];
    __shared__ float vs[64][65];
    __shared__ float ps[32][65];

    const float* qb = Q + (((long)b * HH + h) * TT + q0) * HD;
    for (int i = tid; i < 32 * 64; i += 256) qs[i >> 6][i & 63] = qb[i];

    const int r = tid >> 3, g = tid & 7, dsl = g * 8;
    const int row = q0 + r;
    float acc[8] = {};
    float mrow = -INFINITY, lrow = 0.f;
    const float* kb = Kg + ((long)b * HH + h) * TT * HD;
    const float* vb = V + ((long)b * HH + h) * TT * HD;

    // ---- G: cols 0..31 ----
    for (int i = tid; i < 32 * 64; i += 256) {
        ks[i >> 6][i & 63] = kb[i];
        vs[i >> 6][i & 63] = vb[i];
    }
    __syncthreads();
    {
        float s[4] = {};
        for (int d = 0; d < 64; d++) {
            float qv = qs[r][d];
            #pragma unroll
            for (int j = 0; j < 4; j++) s[j] += qv * ks[g * 4 + j][d];
        }
        float tm = -INFINITY;
        #pragma unroll
        for (int j = 0; j < 4; j++) { s[j] *= 0.125f; tm = fmaxf(tm, s[j]); }
        #pragma unroll
        for (int o = 1; o < 8; o <<= 1) tm = fmaxf(tm, __shfl_xor(tm, o, 64));
        const float newm = tm;
        float psum = 0.f;
        #pragma unroll
        for (int j = 0; j < 4; j++) {
            float p = __expf(s[j] - newm);
            ps[r][g * 4 + j] = p; psum += p;
        }
        #pragma unroll
        for (int o = 1; o < 8; o <<= 1) psum += __shfl_xor(psum, o, 64);
        lrow = psum; mrow = newm;
        #pragma unroll 4
        for (int kk = 0; kk < 32; kk++) {
            float p = ps[r][kk];
            #pragma unroll
            for (int j = 0; j < 8; j++) acc[j] += p * vs[kk][dsl + j];
        }
    }

    // ---- L: band chunks ----
    const int lo = max(32, q0 - 64);
    const int hi = min(TT - 1, q0 + 95);
    for (int c0 = lo; c0 <= hi; c0 += 64) {
        const int W = min(64, hi - c0 + 1);
        __syncthreads();
        for (int i = tid; i < W * 64; i += 256) {
            ks[i >> 6][i & 63] = kb[(long)c0 * 64 + i];
            vs[i >> 6][i & 63] = vb[(long)c0 * 64 + i];
        }
        __syncthreads();
        float s[8] = {};
        for (int d = 0; d < 64; d++) {
            float qv = qs[r][d];
            #pragma unroll
            for (int j = 0; j < 8; j++) s[j] += qv * ks[g * 8 + j][d];
        }
        float tm = -INFINITY;
        #pragma unroll
        for (int j = 0; j < 8; j++) {
            const int kk = g * 8 + j;
            const int dlt = c0 + kk - row;
            const bool act = (kk < W) && dlt <= 64 && dlt >= -64;
            s[j] = act ? s[j] * 0.125f : -INFINITY;
            tm = fmaxf(tm, s[j]);
        }
        #pragma unroll
        for (int o = 1; o < 8; o <<= 1) tm = fmaxf(tm, __shfl_xor(tm, o, 64));
        const float newm = fmaxf(mrow, tm);
        const float corr = (mrow == newm) ? 1.f : __expf(mrow - newm);
        float psum = 0.f;
        #pragma unroll
        for (int j = 0; j < 8; j++) {
            float p = (s[j] == -INFINITY) ? 0.f : __expf(s[j] - newm);
            ps[r][g * 8 + j] = p; psum += p;
        }
        #pragma unroll
        for (int o = 1; o < 8; o <<= 1) psum += __shfl_xor(psum, o, 64);
        lrow = lrow * corr + psum; mrow = newm;
        #pragma unroll
        for (int j = 0; j < 8; j++) acc[j] *= corr;
        #pragma unroll 4
        for (int kk = 0; kk < W; kk++) {
            float p = ps[r][kk];
            #pragma unroll
            for (int j = 0; j < 8; j++) acc[j] += p * vs[kk][dsl + j];
        }
    }

    // ---- R: 16 random cols/row ----
    const int* rr = rand_idx + (long)row * 16;
    {
        float s2[2];
        #pragma unroll
        for (int t = 0; t < 2; t++) {
            const int c = rr[g * 2 + t];
            const float4* kp = (const float4*)(kb + (long)max(c, 0) * HD);
            float sv = 0.f;
            #pragma unroll
            for (int d4 = 0; d4 < 16; d4++) {
                const float4 kv = kp[d4];
                sv += qs[r][d4 * 4 + 0] * kv.x + qs[r][d4 * 4 + 1] * kv.y
                    + qs[r][d4 * 4 + 2] * kv.z + qs[r][d4 * 4 + 3] * kv.w;
            }
            s2[t] = (c >= 0) ? sv * 0.125f : -INFINITY;
        }
        float tm = fmaxf(s2[0], s2[1]);
        #pragma unroll
        for (int o = 1; o < 8; o <<= 1) tm = fmaxf(tm, __shfl_xor(tm, o, 64));
        const float newm = fmaxf(mrow, tm);
        const float corr = (mrow == newm) ? 1.f : __expf(mrow - newm);
        float psum = 0.f;
        #pragma unroll
        for (int t = 0; t < 2; t++) {
            float p = (s2[t] == -INFINITY) ? 0.f : __expf(s2[t] - newm);
            ps[r][g * 2 + t] = p; psum += p;
        }
        #pragma unroll
        for (int o = 1; o < 8; o <<= 1) psum += __shfl_xor(psum, o, 64);
        lrow = lrow * corr + psum; mrow = newm;
        #pragma unroll
        for (int j = 0; j < 8; j++) acc[j] *= corr;
        #pragma unroll 4
        for (int kk = 0; kk < 16; kk++) {
            const float p = ps[r][kk];
            const int c = max(rr[kk], 0);
            const float4* vp = (const float4*)(vb + (long)c * HD + dsl);
            const float4 v0 = vp[0], v1 = vp[1];
            acc[0] += p * v0.x; acc[1] += p * v0.y;
            acc[2] += p * v0.z; acc[3] += p * v0.w;
            acc[4] += p * v1.x; acc[5] += p * v1.y;
            acc[6] += p * v1.z; acc[7] += p * v1.w;
        }
    }

    const float inv = 1.f / lrow;
    const long ob = ((long)b * TT + row) * DD + h * HD + dsl;
    #pragma unroll
    for (int j = 0; j < 8; j++) Ao[ob + j] = (__bf16)(acc[j] * inv);
}

// ---------------------------------------------------------------------------
extern "C" void kernel_launch(void* const* d_in, const int* in_sizes, int n_in,
                              void* d_out, int out_size, void* d_ws, size_t ws_size,
                              hipStream_t stream)
{
    const float* x  = (const float*)d_in[0];
    const float* Wq = (const float*)d_in[1];
    const float* bq = (const float*)d_in[2];
    const float* Wk = (const float*)d_in[3];
    const float* bk = (const float*)d_in[4];
    const float* Wv = (const float*)d_in[5];
    const float* bv = (const float*)d_in[6];
    const float* Wo = (const float*)d_in[7];
    const float* bo = (const float*)d_in[8];
    const void*  mask = d_in[9];

    float* q = (float*)d_ws;
    float* k = q + BTD;
    float* v = k + BTD;
    __bf16* xb   = (__bf16*)(v + BTD);
    __bf16* aob  = xb + BTD;
    __bf16* Wcat = aob + BTD;
    __bf16* Wob  = Wcat + (long)3 * DD * DD;
    int*    rand_idx = (int*)(Wob + (long)DD * DD);
    float*  part = (float*)(rand_idx + (long)TT * 16);

    extract_rand<<<TT - 32, 64, 0, stream>>>(mask, rand_idx);

    const int WN4 = DD * DD / 4;   // 147456
    cvt_bf16<<<(int)(BTD / 4 + 255) / 256, 256, 0, stream>>>(x, xb, (int)(BTD / 4));
    cvt_bf16<<<(WN4 + 255) / 256, 256, 0, stream>>>(Wq, Wcat, WN4);
    cvt_bf16<<<(WN4 + 255) / 256, 256, 0, stream>>>(Wk, Wcat + (long)DD * DD, WN4);
    cvt_bf16<<<(WN4 + 255) / 256, 256, 0, stream>>>(Wv, Wcat + (long)2 * DD * DD, WN4);
    cvt_bf16<<<(WN4 + 255) / 256, 256, 0, stream>>>(Wo, Wob, WN4);

    // QKV fused GEMM: (4096 x 2304) = xb @ Wcat^T, head-layout epilogue
    mfma_gemm<<<dim3(3 * DD / 128, MM / 128), 256, 0, stream>>>(
        xb, Wcat, bq, bk, bv, q, 3 * DD, 1);

    bb_dense_rows<<<dim3(8, HH, BB), 256, 0, stream>>>(q, k, v, part);
    bb_dense_combine<<<dim3(HH, BB), 256, 0, stream>>>(part, aob);
    bb_sparse<<<dim3(TT / 32 - 1, HH, BB), 256, 0, stream>>>(q, k, v, rand_idx, aob);

    // Output GEMM: (4096 x 768) = aob @ Wob^T + bo -> fp32 d_out
    mfma_gemm<<<dim3(DD / 128, MM / 128), 256, 0, stream>>>(
        aob, Wob, bo, bo, bo, (float*)d_out, DD, 0);
}